// Round 1
// baseline (391.637 us; speedup 1.0000x reference)
//
#include <hip/hip_runtime.h>
#include <hip/hip_bf16.h>

// Problem constants (B=2, S=2048, D=1024, H=16, dk=64)
#define B_   2
#define S_   2048
#define H_   16
#define DK_  64
#define D_   1024
#define BS_  4096   // B*S
#define N3_  3072   // 3*D

typedef __attribute__((ext_vector_type(8))) short short8;   // 8 x bf16 (4 VGPRs)
typedef __attribute__((ext_vector_type(4))) float floatx4;  // MFMA 16x16 accumulator
typedef __hip_bfloat16 bf16;

__device__ inline void store_out(bf16* p, float v)  { *p = __float2bfloat16(v); }
__device__ inline void store_out(float* p, float v) { *p = v; }

__device__ inline void load_lds16(const bf16* g, bf16* l) {
    __builtin_amdgcn_global_load_lds(
        (const __attribute__((address_space(1))) void*)g,
        (__attribute__((address_space(3))) void*)l, 16, 0, 0);
}

// ---------------- fp32 -> bf16 convert ----------------
__global__ void cvt_kernel(const float* __restrict__ src, bf16* __restrict__ dst, int n) {
    int i = (blockIdx.x * blockDim.x + threadIdx.x) * 4;
    if (i >= n) return;
    float4 v = *(const float4*)(src + i);
    dst[i + 0] = __float2bfloat16(v.x);
    dst[i + 1] = __float2bfloat16(v.y);
    dst[i + 2] = __float2bfloat16(v.z);
    dst[i + 3] = __float2bfloat16(v.w);
}

// ---------------- GEMM: C[M,N] = A[M,K] * Bw[N,K]^T (B^T layout) ----------------
// m97-style: 128x128 tile, BK=32, global_load_lds width 16, 16x16x32 bf16 MFMA.
template <typename OutT>
__global__ __launch_bounds__(256)
void gemm_bt(const bf16* __restrict__ A, const bf16* __restrict__ Bw,
             OutT* __restrict__ C, int M, int N, int K) {
    __shared__ __align__(16) bf16 lA[128 * 32];
    __shared__ __align__(16) bf16 lB[128 * 32];
    const int t = threadIdx.x;
    const int lane = t & 63, w = t >> 6;
    const int quad = lane >> 4, l16 = lane & 15;
    const int m0 = blockIdx.x * 128, n0 = blockIdx.y * 128;
    const int wm = (w & 1) * 64, wn = (w >> 1) * 64;

    floatx4 acc[4][4];
#pragma unroll
    for (int i = 0; i < 4; i++)
#pragma unroll
        for (int j = 0; j < 4; j++) acc[i][j] = (floatx4){0.f, 0.f, 0.f, 0.f};

    const int srow = t >> 2;        // 0..63
    const int scol = (t & 3) * 8;   // 0,8,16,24
    const bf16* pA0 = A + (size_t)(m0 + srow) * K + scol;
    const bf16* pA1 = A + (size_t)(m0 + 64 + srow) * K + scol;
    const bf16* pB0 = Bw + (size_t)(n0 + srow) * K + scol;
    const bf16* pB1 = Bw + (size_t)(n0 + 64 + srow) * K + scol;
    bf16* dA0 = lA + t * 8;
    bf16* dA1 = lA + 2048 + t * 8;
    bf16* dB0 = lB + t * 8;
    bf16* dB1 = lB + 2048 + t * 8;

    for (int kt = 0; kt < K; kt += 32) {
        load_lds16(pA0, dA0);
        load_lds16(pA1, dA1);
        load_lds16(pB0, dB0);
        load_lds16(pB1, dB1);
        pA0 += 32; pA1 += 32; pB0 += 32; pB1 += 32;
        __syncthreads();   // compiler drains vmcnt before barrier

        short8 af[4], bfr[4];
#pragma unroll
        for (int i = 0; i < 4; i++)
            af[i] = *(const short8*)&lA[(wm + i * 16 + l16) * 32 + quad * 8];
#pragma unroll
        for (int j = 0; j < 4; j++)
            bfr[j] = *(const short8*)&lB[(wn + j * 16 + l16) * 32 + quad * 8];
#pragma unroll
        for (int i = 0; i < 4; i++)
#pragma unroll
            for (int j = 0; j < 4; j++)
                acc[i][j] = __builtin_amdgcn_mfma_f32_16x16x32_bf16(af[i], bfr[j], acc[i][j], 0, 0, 0);
        __syncthreads();
    }

    // C/D layout: col = lane&15, row = (lane>>4)*4 + reg  (m89-verified)
#pragma unroll
    for (int i = 0; i < 4; i++) {
        const int row = m0 + wm + i * 16 + quad * 4;
#pragma unroll
        for (int j = 0; j < 4; j++) {
            const int col = n0 + wn + j * 16 + l16;
#pragma unroll
            for (int r = 0; r < 4; r++)
                store_out(C + (size_t)(row + r) * N + col, acc[i][j][r]);
        }
    }
}

// ---------------- RoPE: QKV (B,S,3D) -> Qr,Kr (B,H,S,64) rotated ----------------
__global__ void rope_kernel(const bf16* __restrict__ QKV,
                            bf16* __restrict__ Qr, bf16* __restrict__ Kr) {
    int tid = blockIdx.x * blockDim.x + threadIdx.x;  // B*S*H*32
    if (tid >= B_ * S_ * H_ * 32) return;
    const int i = tid & 31;
    const int h = (tid >> 5) & (H_ - 1);
    const int bs = tid >> 9;             // b*S + s
    const int s = bs & (S_ - 1);
    const int b = bs >> 11;

    const bf16* base = QKV + (size_t)bs * N3_ + h * 64 + 2 * i;
    const float q0 = __bfloat162float(base[0]);
    const float q1 = __bfloat162float(base[1]);
    const float k0 = __bfloat162float(base[D_]);
    const float k1 = __bfloat162float(base[D_ + 1]);

    const float freq = powf(10000.0f, -(float)(2 * i) * (1.0f / 64.0f));
    const float ang = (float)s * freq;
    float sn, cs;
    sincosf(ang, &sn, &cs);

    const size_t off = ((size_t)(b * H_ + h) * S_ + s) * 64 + 2 * i;
    Qr[off]     = __float2bfloat16(q0 * cs - q1 * sn);
    Qr[off + 1] = __float2bfloat16(q0 * sn + q1 * cs);
    Kr[off]     = __float2bfloat16(k0 * cs - k1 * sn);
    Kr[off + 1] = __float2bfloat16(k0 * sn + k1 * cs);
}

// ---------------- V transpose: QKV V-part (B,S,H,64) -> Vt (B,H,64,S) ----------------
__global__ __launch_bounds__(256)
void vtrans_kernel(const bf16* __restrict__ QKV, bf16* __restrict__ Vt) {
    __shared__ bf16 tile[64][65];
    const int t = threadIdx.x;
    const int bh = blockIdx.y;
    const int b = bh >> 4, h = bh & 15;
    const int s0 = blockIdx.x * 64;

#pragma unroll
    for (int ph = 0; ph < 2; ++ph) {
        const int sr = (t >> 3) + ph * 32;
        const int dc = (t & 7) * 8;
        const bf16* src = QKV + (size_t)(b * S_ + s0 + sr) * N3_ + 2 * D_ + h * 64 + dc;
        short8 v = *(const short8*)src;
        bf16 tmp[8];
        *(short8*)tmp = v;
#pragma unroll
        for (int j = 0; j < 8; j++) tile[sr][dc + j] = tmp[j];
    }
    __syncthreads();
#pragma unroll
    for (int ph = 0; ph < 2; ++ph) {
        const int dr = (t >> 3) + ph * 32;
        const int sc = (t & 7) * 8;
        bf16 tmp[8];
#pragma unroll
        for (int j = 0; j < 8; j++) tmp[j] = tile[sc + j][dr];
        *(short8*)(Vt + ((size_t)bh * 64 + dr) * S_ + s0 + sc) = *(short8*)tmp;
    }
}

// ---------------- Flash attention (causal), one wave = 16 Q rows ----------------
// Qr,Kr: (B,H,S,64) bf16 (RoPE applied); Vt: (B,H,64,S) bf16; Ob: (B,S,H,64) bf16.
__global__ __launch_bounds__(256)
void attn_kernel(const bf16* __restrict__ Qr, const bf16* __restrict__ Kr,
                 const bf16* __restrict__ Vt, bf16* __restrict__ Ob) {
    __shared__ __align__(16) bf16 plds[4][16][32];  // per-wave P tile (16q x 32k)
    const int t = threadIdx.x;
    const int w = t >> 6, lane = t & 63;
    const int quad = lane >> 4, l16 = lane & 15;
    const int bh = blockIdx.y;
    const int b = bh >> 4, h = bh & 15;
    const int q0 = blockIdx.x * 64 + w * 16;

    const bf16* Qb = Qr + (size_t)bh * S_ * 64;
    const bf16* Kb = Kr + (size_t)bh * S_ * 64;
    const bf16* Vb = Vt + (size_t)bh * 64 * S_;

    // Q fragments: A-layout m = lane&15, k = quad*8+j  (two halves of dk=64)
    const short8 aq0 = *(const short8*)(Qb + (size_t)(q0 + l16) * 64 + quad * 8);
    const short8 aq1 = *(const short8*)(Qb + (size_t)(q0 + l16) * 64 + 32 + quad * 8);

    float mrow[4], lrow[4];
    floatx4 o[4];
#pragma unroll
    for (int r = 0; r < 4; r++) { mrow[r] = -1e30f; lrow[r] = 0.f; }
#pragma unroll
    for (int ct = 0; ct < 4; ct++) o[ct] = (floatx4){0.f, 0.f, 0.f, 0.f};

    const int nsteps = (q0 + 16 + 31) >> 5;   // causal: keys < q0+16 only
    for (int st = 0; st < nsteps; ++st) {
        const int kb = st * 32;
        floatx4 s0a = (floatx4){0.f, 0.f, 0.f, 0.f};
        floatx4 s1a = (floatx4){0.f, 0.f, 0.f, 0.f};
        {
            short8 k00 = *(const short8*)(Kb + (size_t)(kb + l16) * 64 + quad * 8);
            short8 k01 = *(const short8*)(Kb + (size_t)(kb + l16) * 64 + 32 + quad * 8);
            s0a = __builtin_amdgcn_mfma_f32_16x16x32_bf16(aq0, k00, s0a, 0, 0, 0);
            s0a = __builtin_amdgcn_mfma_f32_16x16x32_bf16(aq1, k01, s0a, 0, 0, 0);
            short8 k10 = *(const short8*)(Kb + (size_t)(kb + 16 + l16) * 64 + quad * 8);
            short8 k11 = *(const short8*)(Kb + (size_t)(kb + 16 + l16) * 64 + 32 + quad * 8);
            s1a = __builtin_amdgcn_mfma_f32_16x16x32_bf16(aq0, k10, s1a, 0, 0, 0);
            s1a = __builtin_amdgcn_mfma_f32_16x16x32_bf16(aq1, k11, s1a, 0, 0, 0);
        }
        float alpha[4];
#pragma unroll
        for (int r = 0; r < 4; r++) {
            const int q = q0 + quad * 4 + r;
            float v0 = s0a[r] * 0.125f; if (kb + l16 > q)      v0 = -1e30f;
            float v1 = s1a[r] * 0.125f; if (kb + 16 + l16 > q) v1 = -1e30f;
            float rm = fmaxf(v0, v1);
            rm = fmaxf(rm, __shfl_xor(rm, 1));
            rm = fmaxf(rm, __shfl_xor(rm, 2));
            rm = fmaxf(rm, __shfl_xor(rm, 4));
            rm = fmaxf(rm, __shfl_xor(rm, 8));
            const float mnew = fmaxf(mrow[r], rm);
            alpha[r] = __expf(mrow[r] - mnew);
            mrow[r] = mnew;
            const float p0 = __expf(v0 - mnew);
            const float p1 = __expf(v1 - mnew);
            float rs = p0 + p1;
            rs += __shfl_xor(rs, 1);
            rs += __shfl_xor(rs, 2);
            rs += __shfl_xor(rs, 4);
            rs += __shfl_xor(rs, 8);
            lrow[r] = lrow[r] * alpha[r] + rs;
            // P to LDS in C-layout position (row = quad*4+r, col = key)
            plds[w][quad * 4 + r][l16]      = __float2bfloat16(p0);
            plds[w][quad * 4 + r][16 + l16] = __float2bfloat16(p1);
        }
#pragma unroll
        for (int ct = 0; ct < 4; ct++)
#pragma unroll
            for (int r = 0; r < 4; r++) o[ct][r] *= alpha[r];

        // P back in A-layout (same-wave LDS ops are in order; lgkmcnt handled by compiler)
        const short8 ap = *(const short8*)&plds[w][l16][quad * 8];
#pragma unroll
        for (int ct = 0; ct < 4; ct++) {
            short8 bv = *(const short8*)(Vb + (size_t)(ct * 16 + l16) * S_ + kb + quad * 8);
            o[ct] = __builtin_amdgcn_mfma_f32_16x16x32_bf16(ap, bv, o[ct], 0, 0, 0);
        }
    }

#pragma unroll
    for (int r = 0; r < 4; r++) lrow[r] = 1.0f / lrow[r];
#pragma unroll
    for (int ct = 0; ct < 4; ct++)
#pragma unroll
        for (int r = 0; r < 4; r++) {
            const int q = q0 + quad * 4 + r;
            const int d = ct * 16 + l16;
            Ob[((size_t)(b * S_ + q) * H_ + h) * 64 + d] = __float2bfloat16(o[ct][r] * lrow[r]);
        }
}

// ---------------- launch ----------------
extern "C" void kernel_launch(void* const* d_in, const int* in_sizes, int n_in,
                              void* d_out, int out_size, void* d_ws, size_t ws_size,
                              hipStream_t stream) {
    const float* x  = (const float*)d_in[0];
    const float* Wq = (const float*)d_in[1];
    const float* Wk = (const float*)d_in[2];
    const float* Wv = (const float*)d_in[3];
    const float* Wo = (const float*)d_in[4];
    float* out = (float*)d_out;

    char* ws = (char*)d_ws;
    // workspace layout (64 MiB total)
    bf16* xb   = (bf16*)(ws);                       //  8 MiB  (4096x1024)
    bf16* Wcat = (bf16*)(ws + 8388608);             //  6 MiB  (3072x1024)
    bf16* Wob  = (bf16*)(ws + 14680064);            //  2 MiB  (1024x1024)
    bf16* QKVb = (bf16*)(ws + 16777216);            // 24 MiB  (4096x3072)
    bf16* Qr   = (bf16*)(ws + 41943040);            //  8 MiB  (B,H,S,64)
    bf16* Kr   = (bf16*)(ws + 50331648);            //  8 MiB
    bf16* Vt   = (bf16*)(ws + 58720256);            //  8 MiB  (B,H,64,S)
    bf16* Ob   = QKVb;                              // alias: QKV dead after rope+vtrans

    cvt_kernel<<<4096, 256, 0, stream>>>(x, xb, BS_ * D_);
    cvt_kernel<<<1024, 256, 0, stream>>>(Wq, Wcat, D_ * D_);
    cvt_kernel<<<1024, 256, 0, stream>>>(Wk, Wcat + D_ * D_, D_ * D_);
    cvt_kernel<<<1024, 256, 0, stream>>>(Wv, Wcat + 2 * D_ * D_, D_ * D_);
    cvt_kernel<<<1024, 256, 0, stream>>>(Wo, Wob, D_ * D_);

    gemm_bt<bf16><<<dim3(32, 24), 256, 0, stream>>>(xb, Wcat, QKVb, BS_, N3_, D_);
    rope_kernel<<<8192, 256, 0, stream>>>(QKVb, Qr, Kr);
    vtrans_kernel<<<dim3(S_ / 64, B_ * H_), 256, 0, stream>>>(QKVb, Vt);
    attn_kernel<<<dim3(S_ / 64, B_ * H_), 256, 0, stream>>>(Qr, Kr, Vt, Ob);
    gemm_bt<float><<<dim3(32, 8), 256, 0, stream>>>(Ob, Wob, out, BS_, D_, D_);
}